// Round 3
// baseline (251.545 us; speedup 1.0000x reference)
//
#include <hip/hip_runtime.h>
#include <math.h>

#define NFFT 4096
#define LSEG 2048   // L
#define SSZ 4096    // STATE_SIZE

static __device__ __forceinline__ double sigm_f32(float v) {
    return (double)(1.0f / (1.0f + expf(-v)));
}

static __device__ void inv4(const double a[4][4], double out[4][4]) {
    double m[4][8];
    for (int i = 0; i < 4; ++i) {
        for (int j = 0; j < 4; ++j) { m[i][j] = a[i][j]; m[i][j + 4] = (i == j) ? 1.0 : 0.0; }
    }
    for (int c = 0; c < 4; ++c) {
        int piv = c; double best = fabs(m[c][c]);
        for (int r = c + 1; r < 4; ++r) { double v = fabs(m[r][c]); if (v > best) { best = v; piv = r; } }
        if (piv != c) for (int j = 0; j < 8; ++j) { double t = m[c][j]; m[c][j] = m[piv][j]; m[piv][j] = t; }
        double d = 1.0 / m[c][c];
        for (int j = 0; j < 8; ++j) m[c][j] *= d;
        for (int r = 0; r < 4; ++r) {
            if (r == c) continue;
            double f = m[r][c];
            for (int j = 0; j < 8; ++j) m[r][j] -= f * m[c][j];
        }
    }
    for (int i = 0; i < 4; ++i) for (int j = 0; j < 4; ++j) out[i][j] = m[i][j + 4];
}

__global__ void preamp_coef_kernel(const float* __restrict__ cond,
                                   const float* __restrict__ a_rg,
                                   const float* __restrict__ a_r1,
                                   const float* __restrict__ a_c1,
                                   const float* __restrict__ a_c2,
                                   const float* __restrict__ cond_w,
                                   const float* __restrict__ cond_b,
                                   double* __restrict__ coef, int B) {
    int b = blockIdx.x * blockDim.x + threadIdx.x;
    if (b >= B) return;

    const double T = 1.0 / 44100.0;
    const double RG = (0.9 + sigm_f32(a_rg[0]) * 0.2) * 1.0e6;
    const double R1 = (0.99 + sigm_f32(a_r1[0]) * 0.02) * 4.7e5;
    const double C1 = (0.9 + sigm_f32(a_c1[0]) * 0.2) * 3.3e-9;
    const double C2 = (0.9 + sigm_f32(a_c2[0]) * 0.2) * 1.0e-9;
    const double g1 = 1.0 / R1;
    const double gc1 = 2.0 * C1 / T;
    const double gc2 = 2.0 * C2 / T;

    float zf = cond[b] * cond_w[0] + cond_b[0];
    float pot = 1.0f / (1.0f + expf(-zf));
    float pr = (powf(10.0f, pot) - 1.0f) / 9.0f;
    pr = fminf(fmaxf(pr, 1e-4f), 1.0f - 1e-4f);
    double p = (double)pr;

    double So[4][4] = {
        { gc1,     -gc1,      0.0, 1.0},
        {-gc1,      gc1 + g1, 0.0, 0.0},
        { 0.0,      0.0,      gc2, 0.0},
        { 1.0,      0.0,      0.0, 0.0}};
    double S[4][4];
    inv4(So, S);

    double Q00 = S[1][1] - S[1][2] - S[2][1] + S[2][2];
    double Q01 = S[1][2] - S[2][2];
    double Q10 = S[2][1] - S[2][2];
    double Q11 = S[2][2];

    double Ux00 = S[0][1] - S[0][2] - S[1][1] + S[1][2];
    double Ux01 = S[0][2] - S[1][2];
    double Ux10 = S[2][1] - S[2][2];
    double Ux11 = S[2][2];

    double Uo0 = S[2][1] - S[2][2], Uo1 = S[2][2];
    double Uu0 = S[3][1] - S[3][2], Uu1 = S[3][2];

    double P00 = S[0][0] - S[0][1] - S[1][0] + S[1][1];
    double P01 = S[0][2] - S[1][2];
    double P10 = S[2][0] - S[2][1];
    double P11 = S[2][2];

    double Ao00 = 2.0 * gc1 * P00 - 1.0, Ao01 = 2.0 * gc1 * P01;
    double Ao10 = 2.0 * gc2 * P10,       Ao11 = 2.0 * gc2 * P11 - 1.0;

    double Bo0 = 2.0 * gc1 * (S[0][3] - S[1][3]);
    double Bo1 = 2.0 * gc2 * S[2][3];

    double Do0 = S[2][0] - S[2][1], Do1 = S[2][2];
    double Eo  = S[2][3];

    double T00 = 2.0 * gc1 * Ux00, T01 = 2.0 * gc1 * Ux01;
    double T10 = 2.0 * gc2 * Ux10, T11 = 2.0 * gc2 * Ux11;

    double d0 = (1.0 - p) * RG, d1v = p * RG;
    double M00 = d0 + Q00, M01 = Q01, M10 = Q10, M11 = d1v + Q11;
    double idet = 1.0 / (M00 * M11 - M01 * M10);
    double G00 =  M11 * idet, G01 = -M01 * idet;
    double G10 = -M10 * idet, G11 =  M00 * idet;

    double TG00 = T00 * G00 + T01 * G10, TG01 = T00 * G01 + T01 * G11;
    double TG10 = T10 * G00 + T11 * G10, TG11 = T10 * G01 + T11 * G11;

    double A00 = Ao00 - (TG00 * Ux00 + TG01 * Ux01);
    double A01 = Ao01 - (TG00 * Ux10 + TG01 * Ux11);
    double A10 = Ao10 - (TG10 * Ux00 + TG11 * Ux01);
    double A11 = Ao11 - (TG10 * Ux10 + TG11 * Ux11);

    double Bm0 = Bo0 - (TG00 * Uu0 + TG01 * Uu1);
    double Bm1 = Bo1 - (TG10 * Uu0 + TG11 * Uu1);

    double w0v = Uo0 * G00 + Uo1 * G10, w1v = Uo0 * G01 + Uo1 * G11;
    double Dm0 = Do0 - (w0v * Ux00 + w1v * Ux01);
    double Dm1 = Do1 - (w0v * Ux10 + w1v * Ux11);
    double Em  = Eo  - (w0v * Uu0 + w1v * Uu1);

    double den1 = -(A00 + A11);
    double den2 = A00 * A11 - A01 * A10;
    double Mm00 = A00 - Bm0 * Dm0, Mm01 = A01 - Bm0 * Dm1;
    double Mm10 = A10 - Bm1 * Dm0, Mm11 = A11 - Bm1 * Dm1;
    double num0 = Em;
    double num1 = -(Mm00 + Mm11) + (Em - 1.0) * den1;
    double num2 = (Mm00 * Mm11 - Mm01 * Mm10) + (Em - 1.0) * den2;

    coef[(size_t)b * 5 + 0] = num0;
    coef[(size_t)b * 5 + 1] = num1;
    coef[(size_t)b * 5 + 2] = num2;
    coef[(size_t)b * 5 + 3] = den1;
    coef[(size_t)b * 5 + 4] = den2;
}

// ---------------- radix-16 FFT machinery ----------------

static __device__ __forceinline__ float2 cmul(float2 a, float2 b) {
    return make_float2(a.x * b.x - a.y * b.y, a.x * b.y + a.y * b.x);
}
static __device__ __forceinline__ float2 cadd(float2 a, float2 b) { return make_float2(a.x + b.x, a.y + b.y); }
static __device__ __forceinline__ float2 csub(float2 a, float2 b) { return make_float2(a.x - b.x, a.y - b.y); }

static __device__ __forceinline__ int PAD(int i) { return i + (i >> 4); }

template <int SGN>
static __device__ __forceinline__ void dft16(float2 r[16]) {
    const float S = (float)SGN;
    float2 t[16];
#pragma unroll
    for (int n1 = 0; n1 < 4; ++n1) {
        float2 a = r[n1], b = r[n1 + 4], c = r[n1 + 8], d = r[n1 + 12];
        float2 A = cadd(a, c), B = cadd(b, d), C = csub(a, c), D = csub(b, d);
        float2 iD = make_float2(-S * D.y, S * D.x);
        t[n1 * 4 + 0] = cadd(A, B);
        t[n1 * 4 + 1] = cadd(C, iD);
        t[n1 * 4 + 2] = csub(A, B);
        t[n1 * 4 + 3] = csub(C, iD);
    }
    const float CC[10] = {1.f, 0.92387953251f, 0.70710678119f, 0.38268343236f, 0.f,
                          -0.38268343236f, -0.70710678119f, -0.92387953251f, -1.f, -0.92387953251f};
    const float SS[10] = {0.f, 0.38268343236f, 0.70710678119f, 0.92387953251f, 1.f,
                          0.92387953251f, 0.70710678119f, 0.38268343236f, 0.f, -0.38268343236f};
#pragma unroll
    for (int n1 = 1; n1 < 4; ++n1) {
#pragma unroll
        for (int m2 = 1; m2 < 4; ++m2) {
            const int k = n1 * m2;
            t[n1 * 4 + m2] = cmul(t[n1 * 4 + m2], make_float2(CC[k], S * SS[k]));
        }
    }
#pragma unroll
    for (int m2 = 0; m2 < 4; ++m2) {
        float2 a = t[m2], b = t[4 + m2], c = t[8 + m2], d = t[12 + m2];
        float2 A = cadd(a, c), B = cadd(b, d), C = csub(a, c), D = csub(b, d);
        float2 iD = make_float2(-S * D.y, S * D.x);
        r[m2]      = cadd(A, B);
        r[m2 + 4]  = cadd(C, iD);
        r[m2 + 8]  = csub(A, B);
        r[m2 + 12] = csub(C, iD);
    }
}

// apply r[m] *= w1^m via squaring tree (depth 4, better accuracy & ILP)
static __device__ __forceinline__ void twiddle_chain(float2 r[16], float2 w1) {
    float2 w2 = cmul(w1, w1);
    float2 w3 = cmul(w2, w1);
    float2 w4 = cmul(w2, w2);
    float2 w5 = cmul(w4, w1);
    float2 w6 = cmul(w4, w2);
    float2 w7 = cmul(w4, w3);
    float2 w8 = cmul(w4, w4);
    r[1] = cmul(r[1], w1);   r[2] = cmul(r[2], w2);
    r[3] = cmul(r[3], w3);   r[4] = cmul(r[4], w4);
    r[5] = cmul(r[5], w5);   r[6] = cmul(r[6], w6);
    r[7] = cmul(r[7], w7);   r[8] = cmul(r[8], w8);
    r[9]  = cmul(r[9],  cmul(w8, w1));
    r[10] = cmul(r[10], cmul(w8, w2));
    r[11] = cmul(r[11], cmul(w8, w3));
    r[12] = cmul(r[12], cmul(w8, w4));
    r[13] = cmul(r[13], cmul(w8, w5));
    r[14] = cmul(r[14], cmul(w8, w6));
    r[15] = cmul(r[15], cmul(w8, w7));
}

// fp64 Horner for num/den at z = (zr,zi), fp32 complex divide (cancellation is
// in the sums, not the divide; v_rcp_f32 rel err ~1e-7 << 8e-3 threshold)
static __device__ __forceinline__ float2 eval_h(double n0, double n1, double n2,
                                                double d1, double d2,
                                                double zr, double zi) {
    double ar = n0 * zr + n1, ai = n0 * zi;
    double nr = ar * zr - ai * zi + n2, ni = ar * zi + ai * zr;
    double br = zr + d1, bi = zi;
    double dr = br * zr - bi * zi + d2, di = br * zi + bi * zr;
    float fnr = (float)nr, fni = (float)ni, fdr = (float)dr, fdi = (float)di;
    float idn = __builtin_amdgcn_rcpf(fdr * fdr + fdi * fdi);
    return make_float2((fnr * fdr + fni * fdi) * idn,
                       (fni * fdr - fnr * fdi) * idn);
}

// One block per PAIR of batches: w[n] = sig_a[n] + i*sig_b[n]; one complex FFT;
// Hermitian split; per-batch H; recombine Y = Ha*Xa + i*Hb*Xb; one inverse FFT;
// y_a = Re, y_b = Im.
__global__ __launch_bounds__(256, 4)
void preamp_fft_kernel(const float* __restrict__ x,
                       const float* __restrict__ state,
                       const double* __restrict__ coef,
                       float* __restrict__ out, int B) {
    __shared__ float2 a_s[NFFT + NFFT / 16];   // padded: 34 KB

    const int t = threadIdx.x;
    const int b0 = 2 * blockIdx.x;
    const int b1 = (b0 + 1 < B) ? b0 + 1 : b0;

    const float* st0 = state + (size_t)b0 * SSZ + (SSZ - LSEG);
    const float* xb0 = x + (size_t)b0 * LSEG;
    const float* st1 = state + (size_t)b1 * SSZ + (SSZ - LSEG);
    const float* xb1 = x + (size_t)b1 * LSEG;

    for (int i = t; i < NFFT; i += 256) {
        float fa, fb;
        if (i < LSEG) { fa = st0[i]; fb = st1[i]; }
        else          { fa = xb0[i - LSEG]; fb = xb1[i - LSEG]; }
        a_s[PAD(i)] = make_float2(fa, fb);
    }
    const double na0 = coef[(size_t)b0 * 5 + 0];
    const double na1 = coef[(size_t)b0 * 5 + 1];
    const double na2 = coef[(size_t)b0 * 5 + 2];
    const double da1 = coef[(size_t)b0 * 5 + 3];
    const double da2 = coef[(size_t)b0 * 5 + 4];
    const double nb0 = coef[(size_t)b1 * 5 + 0];
    const double nb1 = coef[(size_t)b1 * 5 + 1];
    const double nb2 = coef[(size_t)b1 * 5 + 2];
    const double db1 = coef[(size_t)b1 * 5 + 3];
    const double db2 = coef[(size_t)b1 * 5 + 4];
    __syncthreads();

    const float TW4096 = 0.00153398078788564f;  // 2*pi/4096
    const float TW256  = 0.02454369260617026f;  // 2*pi/256

    float2 r[16];

    // ---- forward pass A: span 256 ----
#pragma unroll
    for (int m = 0; m < 16; ++m) r[m] = a_s[PAD(t + 256 * m)];
    dft16<-1>(r);
    {
        float sw, cw;
        __sincosf((float)t * TW4096, &sw, &cw);
        twiddle_chain(r, make_float2(cw, -sw));
    }
#pragma unroll
    for (int m = 0; m < 16; ++m) a_s[PAD(t + 256 * m)] = r[m];
    __syncthreads();

    // ---- forward pass B: span 16 within 256-blocks ----
    {
        const int sub = t >> 4, j = t & 15;
        const int base = sub * 256 + j;
#pragma unroll
        for (int m = 0; m < 16; ++m) r[m] = a_s[PAD(base + 16 * m)];
        dft16<-1>(r);
        float sw, cw;
        __sincosf((float)j * TW256, &sw, &cw);
        twiddle_chain(r, make_float2(cw, -sw));
#pragma unroll
        for (int m = 0; m < 16; ++m) a_s[PAD(base + 16 * m)] = r[m];
    }
    __syncthreads();

    // ---- fused middle: span-1 fwd DFT + Hermitian split + H + recombine + span-1 inv ----
    {
        const int base = 16 * t;
#pragma unroll
        for (int m = 0; m < 16; ++m) r[m] = a_s[PAD(base + m)];
        dft16<-1>(r);
        // position 16t+m holds W[k], k = (m<<8) | klo
        const int klo = ((t & 15) << 4) | (t >> 4);
        __syncthreads();
        // scatter W to natural order
#pragma unroll
        for (int m = 0; m < 16; ++m) a_s[PAD((m << 8) | klo)] = r[m];
        __syncthreads();
#pragma unroll
        for (int m = 0; m < 16; ++m) {
            const int k = (m << 8) | klo;
            const int kr = (NFFT - k) & (NFFT - 1);
            float2 Wr = a_s[PAD(kr)];
            float2 Wk = r[m];
            // Hermitian split
            float Xar = 0.5f * (Wk.x + Wr.x), Xai = 0.5f * (Wk.y - Wr.y);
            float Xbr = 0.5f * (Wk.y + Wr.y), Xbi = 0.5f * (Wr.x - Wk.x);
            // z_k = e^{-i 2pi k/N}
            float sw, cw;
            __sincosf((float)k * TW4096, &sw, &cw);
            const double zr = (double)cw, zi = -(double)sw;
            float2 Ha = eval_h(na0, na1, na2, da1, da2, zr, zi);
            float2 Hb = eval_h(nb0, nb1, nb2, db1, db2, zr, zi);
            float Yar = Ha.x * Xar - Ha.y * Xai, Yai = Ha.x * Xai + Ha.y * Xar;
            float Ybr = Hb.x * Xbr - Hb.y * Xbi, Ybi = Hb.x * Xbi + Hb.y * Xbr;
            r[m] = make_float2(Yar - Ybi, Yai + Ybr);
        }
        __syncthreads();   // all partner reads done before overwriting
        dft16<1>(r);
#pragma unroll
        for (int m = 0; m < 16; ++m) a_s[PAD(base + m)] = r[m];
    }
    __syncthreads();

    // ---- inverse pass B ----
    {
        const int sub = t >> 4, j = t & 15;
        const int base = sub * 256 + j;
#pragma unroll
        for (int m = 0; m < 16; ++m) r[m] = a_s[PAD(base + 16 * m)];
        float sw, cw;
        __sincosf((float)j * TW256, &sw, &cw);
        twiddle_chain(r, make_float2(cw, sw));
        dft16<1>(r);
#pragma unroll
        for (int m = 0; m < 16; ++m) a_s[PAD(base + 16 * m)] = r[m];
    }
    __syncthreads();

    // ---- inverse pass A + direct store of last 2048 samples of both batches ----
    {
#pragma unroll
        for (int m = 0; m < 16; ++m) r[m] = a_s[PAD(t + 256 * m)];
        float sw, cw;
        __sincosf((float)t * TW4096, &sw, &cw);
        twiddle_chain(r, make_float2(cw, sw));
        dft16<1>(r);
        const float scale = 1.0f / (float)NFFT;
        float* ob0 = out + (size_t)b0 * LSEG;
        float* ob1 = out + (size_t)b1 * LSEG;
#pragma unroll
        for (int m = 8; m < 16; ++m) {
            ob0[t + 256 * (m - 8)] = r[m].x * scale;
            if (b1 != b0) ob1[t + 256 * (m - 8)] = r[m].y * scale;
        }
    }
}

extern "C" void kernel_launch(void* const* d_in, const int* in_sizes, int n_in,
                              void* d_out, int out_size, void* d_ws, size_t ws_size,
                              hipStream_t stream) {
    const float* x     = (const float*)d_in[0];
    const float* cond  = (const float*)d_in[1];
    const float* state = (const float*)d_in[2];
    const float* a_rg  = (const float*)d_in[3];
    const float* a_r1  = (const float*)d_in[4];
    const float* a_c1  = (const float*)d_in[5];
    const float* a_c2  = (const float*)d_in[6];
    const float* c_w   = (const float*)d_in[7];
    const float* c_b   = (const float*)d_in[8];
    float* out = (float*)d_out;

    const int B = in_sizes[1];          // cond is [B,1]
    double* coef = (double*)d_ws;       // B*5 doubles

    preamp_coef_kernel<<<dim3((B + 255) / 256), dim3(256), 0, stream>>>(
        cond, a_rg, a_r1, a_c1, a_c2, c_w, c_b, coef, B);
    preamp_fft_kernel<<<dim3((B + 1) / 2), dim3(256), 0, stream>>>(x, state, coef, out, B);
}

// Round 4
// 126.198 us; speedup vs baseline: 1.9933x; 1.9933x over previous
//
#include <hip/hip_runtime.h>
#include <math.h>

#define NFFT 4096
#define HALF 2048
#define LSEG 2048   // L
#define SSZ 4096    // STATE_SIZE

static __device__ __forceinline__ double sigm_f32(float v) {
    return (double)(1.0f / (1.0f + expf(-v)));
}

static __device__ void inv4(const double a[4][4], double out[4][4]) {
    double m[4][8];
    for (int i = 0; i < 4; ++i) {
        for (int j = 0; j < 4; ++j) { m[i][j] = a[i][j]; m[i][j + 4] = (i == j) ? 1.0 : 0.0; }
    }
    for (int c = 0; c < 4; ++c) {
        int piv = c; double best = fabs(m[c][c]);
        for (int r = c + 1; r < 4; ++r) { double v = fabs(m[r][c]); if (v > best) { best = v; piv = r; } }
        if (piv != c) for (int j = 0; j < 8; ++j) { double t = m[c][j]; m[c][j] = m[piv][j]; m[piv][j] = t; }
        double d = 1.0 / m[c][c];
        for (int j = 0; j < 8; ++j) m[c][j] *= d;
        for (int r = 0; r < 4; ++r) {
            if (r == c) continue;
            double f = m[r][c];
            for (int j = 0; j < 8; ++j) m[r][j] -= f * m[c][j];
        }
    }
    for (int i = 0; i < 4; ++i) for (int j = 0; j < 4; ++j) out[i][j] = m[i][j + 4];
}

__global__ void preamp_coef_kernel(const float* __restrict__ cond,
                                   const float* __restrict__ a_rg,
                                   const float* __restrict__ a_r1,
                                   const float* __restrict__ a_c1,
                                   const float* __restrict__ a_c2,
                                   const float* __restrict__ cond_w,
                                   const float* __restrict__ cond_b,
                                   double* __restrict__ coef, int B) {
    int b = blockIdx.x * blockDim.x + threadIdx.x;
    if (b >= B) return;

    const double T = 1.0 / 44100.0;
    const double RG = (0.9 + sigm_f32(a_rg[0]) * 0.2) * 1.0e6;
    const double R1 = (0.99 + sigm_f32(a_r1[0]) * 0.02) * 4.7e5;
    const double C1 = (0.9 + sigm_f32(a_c1[0]) * 0.2) * 3.3e-9;
    const double C2 = (0.9 + sigm_f32(a_c2[0]) * 0.2) * 1.0e-9;
    const double g1 = 1.0 / R1;
    const double gc1 = 2.0 * C1 / T;
    const double gc2 = 2.0 * C2 / T;

    float zf = cond[b] * cond_w[0] + cond_b[0];
    float pot = 1.0f / (1.0f + expf(-zf));
    float pr = (powf(10.0f, pot) - 1.0f) / 9.0f;
    pr = fminf(fmaxf(pr, 1e-4f), 1.0f - 1e-4f);
    double p = (double)pr;

    double So[4][4] = {
        { gc1,     -gc1,      0.0, 1.0},
        {-gc1,      gc1 + g1, 0.0, 0.0},
        { 0.0,      0.0,      gc2, 0.0},
        { 1.0,      0.0,      0.0, 0.0}};
    double S[4][4];
    inv4(So, S);

    double Q00 = S[1][1] - S[1][2] - S[2][1] + S[2][2];
    double Q01 = S[1][2] - S[2][2];
    double Q10 = S[2][1] - S[2][2];
    double Q11 = S[2][2];

    double Ux00 = S[0][1] - S[0][2] - S[1][1] + S[1][2];
    double Ux01 = S[0][2] - S[1][2];
    double Ux10 = S[2][1] - S[2][2];
    double Ux11 = S[2][2];

    double Uo0 = S[2][1] - S[2][2], Uo1 = S[2][2];
    double Uu0 = S[3][1] - S[3][2], Uu1 = S[3][2];

    double P00 = S[0][0] - S[0][1] - S[1][0] + S[1][1];
    double P01 = S[0][2] - S[1][2];
    double P10 = S[2][0] - S[2][1];
    double P11 = S[2][2];

    double Ao00 = 2.0 * gc1 * P00 - 1.0, Ao01 = 2.0 * gc1 * P01;
    double Ao10 = 2.0 * gc2 * P10,       Ao11 = 2.0 * gc2 * P11 - 1.0;

    double Bo0 = 2.0 * gc1 * (S[0][3] - S[1][3]);
    double Bo1 = 2.0 * gc2 * S[2][3];

    double Do0 = S[2][0] - S[2][1], Do1 = S[2][2];
    double Eo  = S[2][3];

    double T00 = 2.0 * gc1 * Ux00, T01 = 2.0 * gc1 * Ux01;
    double T10 = 2.0 * gc2 * Ux10, T11 = 2.0 * gc2 * Ux11;

    double d0 = (1.0 - p) * RG, d1v = p * RG;
    double M00 = d0 + Q00, M01 = Q01, M10 = Q10, M11 = d1v + Q11;
    double idet = 1.0 / (M00 * M11 - M01 * M10);
    double G00 =  M11 * idet, G01 = -M01 * idet;
    double G10 = -M10 * idet, G11 =  M00 * idet;

    double TG00 = T00 * G00 + T01 * G10, TG01 = T00 * G01 + T01 * G11;
    double TG10 = T10 * G00 + T11 * G10, TG11 = T10 * G01 + T11 * G11;

    double A00 = Ao00 - (TG00 * Ux00 + TG01 * Ux01);
    double A01 = Ao01 - (TG00 * Ux10 + TG01 * Ux11);
    double A10 = Ao10 - (TG10 * Ux00 + TG11 * Ux01);
    double A11 = Ao11 - (TG10 * Ux10 + TG11 * Ux11);

    double Bm0 = Bo0 - (TG00 * Uu0 + TG01 * Uu1);
    double Bm1 = Bo1 - (TG10 * Uu0 + TG11 * Uu1);

    double w0v = Uo0 * G00 + Uo1 * G10, w1v = Uo0 * G01 + Uo1 * G11;
    double Dm0 = Do0 - (w0v * Ux00 + w1v * Ux01);
    double Dm1 = Do1 - (w0v * Ux10 + w1v * Ux11);
    double Em  = Eo  - (w0v * Uu0 + w1v * Uu1);

    double den1 = -(A00 + A11);
    double den2 = A00 * A11 - A01 * A10;
    double Mm00 = A00 - Bm0 * Dm0, Mm01 = A01 - Bm0 * Dm1;
    double Mm10 = A10 - Bm1 * Dm0, Mm11 = A11 - Bm1 * Dm1;
    double num0 = Em;
    double num1 = -(Mm00 + Mm11) + (Em - 1.0) * den1;
    double num2 = (Mm00 * Mm11 - Mm01 * Mm10) + (Em - 1.0) * den2;

    coef[(size_t)b * 5 + 0] = num0;
    coef[(size_t)b * 5 + 1] = num1;
    coef[(size_t)b * 5 + 2] = num2;
    coef[(size_t)b * 5 + 3] = den1;
    coef[(size_t)b * 5 + 4] = den2;
}

// ---------------- radix-16 FFT machinery ----------------

static __device__ __forceinline__ float2 cmul(float2 a, float2 b) {
    return make_float2(a.x * b.x - a.y * b.y, a.x * b.y + a.y * b.x);
}
static __device__ __forceinline__ float2 cadd(float2 a, float2 b) { return make_float2(a.x + b.x, a.y + b.y); }
static __device__ __forceinline__ float2 csub(float2 a, float2 b) { return make_float2(a.x - b.x, a.y - b.y); }

static __device__ __forceinline__ int PAD(int i) { return i + (i >> 4); }

template <int SGN>
static __device__ __forceinline__ void dft16(float2 r[16]) {
    const float S = (float)SGN;
    float2 t[16];
#pragma unroll
    for (int n1 = 0; n1 < 4; ++n1) {
        float2 a = r[n1], b = r[n1 + 4], c = r[n1 + 8], d = r[n1 + 12];
        float2 A = cadd(a, c), B = cadd(b, d), C = csub(a, c), D = csub(b, d);
        float2 iD = make_float2(-S * D.y, S * D.x);
        t[n1 * 4 + 0] = cadd(A, B);
        t[n1 * 4 + 1] = cadd(C, iD);
        t[n1 * 4 + 2] = csub(A, B);
        t[n1 * 4 + 3] = csub(C, iD);
    }
    const float CC[10] = {1.f, 0.92387953251f, 0.70710678119f, 0.38268343236f, 0.f,
                          -0.38268343236f, -0.70710678119f, -0.92387953251f, -1.f, -0.92387953251f};
    const float SS[10] = {0.f, 0.38268343236f, 0.70710678119f, 0.92387953251f, 1.f,
                          0.92387953251f, 0.70710678119f, 0.38268343236f, 0.f, -0.38268343236f};
#pragma unroll
    for (int n1 = 1; n1 < 4; ++n1) {
#pragma unroll
        for (int m2 = 1; m2 < 4; ++m2) {
            const int k = n1 * m2;
            t[n1 * 4 + m2] = cmul(t[n1 * 4 + m2], make_float2(CC[k], S * SS[k]));
        }
    }
#pragma unroll
    for (int m2 = 0; m2 < 4; ++m2) {
        float2 a = t[m2], b = t[4 + m2], c = t[8 + m2], d = t[12 + m2];
        float2 A = cadd(a, c), B = cadd(b, d), C = csub(a, c), D = csub(b, d);
        float2 iD = make_float2(-S * D.y, S * D.x);
        r[m2]      = cadd(A, B);
        r[m2 + 4]  = cadd(C, iD);
        r[m2 + 8]  = csub(A, B);
        r[m2 + 12] = csub(C, iD);
    }
}

// apply r[m] *= w1^m via squaring tree (depth 4, better accuracy & ILP)
static __device__ __forceinline__ void twiddle_chain(float2 r[16], float2 w1) {
    float2 w2 = cmul(w1, w1);
    float2 w3 = cmul(w2, w1);
    float2 w4 = cmul(w2, w2);
    float2 w5 = cmul(w4, w1);
    float2 w6 = cmul(w4, w2);
    float2 w7 = cmul(w4, w3);
    float2 w8 = cmul(w4, w4);
    r[1] = cmul(r[1], w1);   r[2] = cmul(r[2], w2);
    r[3] = cmul(r[3], w3);   r[4] = cmul(r[4], w4);
    r[5] = cmul(r[5], w5);   r[6] = cmul(r[6], w6);
    r[7] = cmul(r[7], w7);   r[8] = cmul(r[8], w8);
    r[9]  = cmul(r[9],  cmul(w8, w1));
    r[10] = cmul(r[10], cmul(w8, w2));
    r[11] = cmul(r[11], cmul(w8, w3));
    r[12] = cmul(r[12], cmul(w8, w4));
    r[13] = cmul(r[13], cmul(w8, w5));
    r[14] = cmul(r[14], cmul(w8, w6));
    r[15] = cmul(r[15], cmul(w8, w7));
}

// fp64 Horner for num/den at z = (zr,zi), fp32 complex divide
static __device__ __forceinline__ float2 eval_h(double n0, double n1, double n2,
                                                double d1, double d2,
                                                double zr, double zi) {
    double ar = n0 * zr + n1, ai = n0 * zi;
    double nr = ar * zr - ai * zi + n2, ni = ar * zi + ai * zr;
    double br = zr + d1, bi = zi;
    double dr = br * zr - bi * zi + d2, di = br * zi + bi * zr;
    float fnr = (float)nr, fni = (float)ni, fdr = (float)dr, fdi = (float)di;
    float idn = __builtin_amdgcn_rcpf(fdr * fdr + fdi * fdi);
    return make_float2((fnr * fdr + fni * fdi) * idn,
                       (fni * fdr - fnr * fdi) * idn);
}

// One block per PAIR of batches: w[n] = sig_a[n] + i*sig_b[n]; one complex FFT;
// Hermitian-pair pointwise in natural order (H(z_{N-k}) = conj H(z_k));
// one inverse FFT; y_a = Re, y_b = Im.
__global__ __launch_bounds__(256)
void preamp_fft_kernel(const float* __restrict__ x,
                       const float* __restrict__ state,
                       const double* __restrict__ coef,
                       float* __restrict__ out, int B) {
    __shared__ float2 a_s[NFFT + NFFT / 16];   // padded: 34 KB

    const int t = threadIdx.x;
    const int b0 = 2 * blockIdx.x;
    const int b1 = (b0 + 1 < B) ? b0 + 1 : b0;

    const float* st0 = state + (size_t)b0 * SSZ + (SSZ - LSEG);
    const float* xb0 = x + (size_t)b0 * LSEG;
    const float* st1 = state + (size_t)b1 * SSZ + (SSZ - LSEG);
    const float* xb1 = x + (size_t)b1 * LSEG;

    for (int i = t; i < NFFT; i += 256) {
        float fa, fb;
        if (i < LSEG) { fa = st0[i]; fb = st1[i]; }
        else          { fa = xb0[i - LSEG]; fb = xb1[i - LSEG]; }
        a_s[PAD(i)] = make_float2(fa, fb);
    }
    __syncthreads();

    const float TW4096 = 0.00153398078788564f;  // 2*pi/4096
    const float TW256  = 0.02454369260617026f;  // 2*pi/256

    float2 r[16];

    // ---- forward pass A: span 256 ----
#pragma unroll
    for (int m = 0; m < 16; ++m) r[m] = a_s[PAD(t + 256 * m)];
    dft16<-1>(r);
    {
        float sw, cw;
        __sincosf((float)t * TW4096, &sw, &cw);
        twiddle_chain(r, make_float2(cw, -sw));
    }
#pragma unroll
    for (int m = 0; m < 16; ++m) a_s[PAD(t + 256 * m)] = r[m];
    __syncthreads();

    // ---- forward pass B: span 16 within 256-blocks ----
    {
        const int sub = t >> 4, j = t & 15;
        const int base = sub * 256 + j;
#pragma unroll
        for (int m = 0; m < 16; ++m) r[m] = a_s[PAD(base + 16 * m)];
        dft16<-1>(r);
        float sw, cw;
        __sincosf((float)j * TW256, &sw, &cw);
        twiddle_chain(r, make_float2(cw, -sw));
#pragma unroll
        for (int m = 0; m < 16; ++m) a_s[PAD(base + 16 * m)] = r[m];
    }
    __syncthreads();

    // ---- forward span-1 DFT, scatter to natural order ----
    {
        const int base = 16 * t;
#pragma unroll
        for (int m = 0; m < 16; ++m) r[m] = a_s[PAD(base + m)];
        dft16<-1>(r);
        const int klo = ((t & 15) << 4) | (t >> 4);
        __syncthreads();
#pragma unroll
        for (int m = 0; m < 16; ++m) a_s[PAD((m << 8) | klo)] = r[m];
    }
    __syncthreads();

    // ---- pointwise in natural order over Hermitian pairs (k, N-k) ----
    {
        const double na0 = coef[(size_t)b0 * 5 + 0];
        const double na1 = coef[(size_t)b0 * 5 + 1];
        const double na2 = coef[(size_t)b0 * 5 + 2];
        const double da1 = coef[(size_t)b0 * 5 + 3];
        const double da2 = coef[(size_t)b0 * 5 + 4];
        const double nb0 = coef[(size_t)b1 * 5 + 0];
        const double nb1 = coef[(size_t)b1 * 5 + 1];
        const double nb2 = coef[(size_t)b1 * 5 + 2];
        const double db1 = coef[(size_t)b1 * 5 + 3];
        const double db2 = coef[(size_t)b1 * 5 + 4];

        // i = 0..2048 inclusive: i==0 and i==2048 are self-paired bins.
        for (int i = t; i <= HALF; i += 256) {
            const int k  = i;
            const int kr = (NFFT - i) & (NFFT - 1);
            float2 Wk = a_s[PAD(k)];
            float2 Wr = a_s[PAD(kr)];
            // Hermitian split
            float Xar = 0.5f * (Wk.x + Wr.x), Xai = 0.5f * (Wk.y - Wr.y);
            float Xbr = 0.5f * (Wk.y + Wr.y), Xbi = 0.5f * (Wr.x - Wk.x);
            float sw, cw;
            __sincosf((float)k * TW4096, &sw, &cw);
            const double zr = (double)cw, zi = -(double)sw;
            float2 Ha = eval_h(na0, na1, na2, da1, da2, zr, zi);
            float2 Hb = eval_h(nb0, nb1, nb2, db1, db2, zr, zi);
            float Yar = Ha.x * Xar - Ha.y * Xai, Yai = Ha.x * Xai + Ha.y * Xar;
            float Ybr = Hb.x * Xbr - Hb.y * Xbi, Ybi = Hb.x * Xbi + Hb.y * Xbr;
            // Y[k] = Ya + i*Yb
            a_s[PAD(k)] = make_float2(Yar - Ybi, Yai + Ybr);
            // Y[N-k] = conj(Ya) + i*conj(Yb)
            if (kr != k) a_s[PAD(kr)] = make_float2(Yar + Ybi, Ybr - Yai);
        }
    }
    __syncthreads();

    // ---- inverse span-1: gather from natural order, DFT, store span-1 layout ----
    {
        const int base = 16 * t;
        const int klo = ((t & 15) << 4) | (t >> 4);
#pragma unroll
        for (int m = 0; m < 16; ++m) r[m] = a_s[PAD((m << 8) | klo)];
        dft16<1>(r);
        __syncthreads();
#pragma unroll
        for (int m = 0; m < 16; ++m) a_s[PAD(base + m)] = r[m];
    }
    __syncthreads();

    // ---- inverse pass B ----
    {
        const int sub = t >> 4, j = t & 15;
        const int base = sub * 256 + j;
#pragma unroll
        for (int m = 0; m < 16; ++m) r[m] = a_s[PAD(base + 16 * m)];
        float sw, cw;
        __sincosf((float)j * TW256, &sw, &cw);
        twiddle_chain(r, make_float2(cw, sw));
        dft16<1>(r);
#pragma unroll
        for (int m = 0; m < 16; ++m) a_s[PAD(base + 16 * m)] = r[m];
    }
    __syncthreads();

    // ---- inverse pass A + direct store of last 2048 samples of both batches ----
    {
#pragma unroll
        for (int m = 0; m < 16; ++m) r[m] = a_s[PAD(t + 256 * m)];
        float sw, cw;
        __sincosf((float)t * TW4096, &sw, &cw);
        twiddle_chain(r, make_float2(cw, sw));
        dft16<1>(r);
        const float scale = 1.0f / (float)NFFT;
        float* ob0 = out + (size_t)b0 * LSEG;
        float* ob1 = out + (size_t)b1 * LSEG;
#pragma unroll
        for (int m = 8; m < 16; ++m) {
            ob0[t + 256 * (m - 8)] = r[m].x * scale;
            if (b1 != b0) ob1[t + 256 * (m - 8)] = r[m].y * scale;
        }
    }
}

extern "C" void kernel_launch(void* const* d_in, const int* in_sizes, int n_in,
                              void* d_out, int out_size, void* d_ws, size_t ws_size,
                              hipStream_t stream) {
    const float* x     = (const float*)d_in[0];
    const float* cond  = (const float*)d_in[1];
    const float* state = (const float*)d_in[2];
    const float* a_rg  = (const float*)d_in[3];
    const float* a_r1  = (const float*)d_in[4];
    const float* a_c1  = (const float*)d_in[5];
    const float* a_c2  = (const float*)d_in[6];
    const float* c_w   = (const float*)d_in[7];
    const float* c_b   = (const float*)d_in[8];
    float* out = (float*)d_out;

    const int B = in_sizes[1];          // cond is [B,1]
    double* coef = (double*)d_ws;       // B*5 doubles

    preamp_coef_kernel<<<dim3((B + 255) / 256), dim3(256), 0, stream>>>(
        cond, a_rg, a_r1, a_c1, a_c2, c_w, c_b, coef, B);
    preamp_fft_kernel<<<dim3((B + 1) / 2), dim3(256), 0, stream>>>(x, state, coef, out, B);
}

// Round 5
// 121.442 us; speedup vs baseline: 2.0713x; 1.0392x over previous
//
#include <hip/hip_runtime.h>
#include <math.h>

#define NFFT 4096
#define HALF 2048
#define LSEG 2048   // L
#define SSZ 4096    // STATE_SIZE

// ---------------- radix-16 FFT machinery ----------------

static __device__ __forceinline__ float2 cmul(float2 a, float2 b) {
    return make_float2(a.x * b.x - a.y * b.y, a.x * b.y + a.y * b.x);
}
static __device__ __forceinline__ float2 cadd(float2 a, float2 b) { return make_float2(a.x + b.x, a.y + b.y); }
static __device__ __forceinline__ float2 csub(float2 a, float2 b) { return make_float2(a.x - b.x, a.y - b.y); }

static __device__ __forceinline__ int PAD(int i) { return i + (i >> 4); }

template <int SGN>
static __device__ __forceinline__ void dft16(float2 r[16]) {
    const float S = (float)SGN;
    float2 t[16];
#pragma unroll
    for (int n1 = 0; n1 < 4; ++n1) {
        float2 a = r[n1], b = r[n1 + 4], c = r[n1 + 8], d = r[n1 + 12];
        float2 A = cadd(a, c), B = cadd(b, d), C = csub(a, c), D = csub(b, d);
        float2 iD = make_float2(-S * D.y, S * D.x);
        t[n1 * 4 + 0] = cadd(A, B);
        t[n1 * 4 + 1] = cadd(C, iD);
        t[n1 * 4 + 2] = csub(A, B);
        t[n1 * 4 + 3] = csub(C, iD);
    }
    const float CC[10] = {1.f, 0.92387953251f, 0.70710678119f, 0.38268343236f, 0.f,
                          -0.38268343236f, -0.70710678119f, -0.92387953251f, -1.f, -0.92387953251f};
    const float SS[10] = {0.f, 0.38268343236f, 0.70710678119f, 0.92387953251f, 1.f,
                          0.92387953251f, 0.70710678119f, 0.38268343236f, 0.f, -0.38268343236f};
#pragma unroll
    for (int n1 = 1; n1 < 4; ++n1) {
#pragma unroll
        for (int m2 = 1; m2 < 4; ++m2) {
            const int k = n1 * m2;
            t[n1 * 4 + m2] = cmul(t[n1 * 4 + m2], make_float2(CC[k], S * SS[k]));
        }
    }
#pragma unroll
    for (int m2 = 0; m2 < 4; ++m2) {
        float2 a = t[m2], b = t[4 + m2], c = t[8 + m2], d = t[12 + m2];
        float2 A = cadd(a, c), B = cadd(b, d), C = csub(a, c), D = csub(b, d);
        float2 iD = make_float2(-S * D.y, S * D.x);
        r[m2]      = cadd(A, B);
        r[m2 + 4]  = cadd(C, iD);
        r[m2 + 8]  = csub(A, B);
        r[m2 + 12] = csub(C, iD);
    }
}

// apply r[m] *= w1^m via squaring tree (depth 4, better accuracy & ILP)
static __device__ __forceinline__ void twiddle_chain(float2 r[16], float2 w1) {
    float2 w2 = cmul(w1, w1);
    float2 w3 = cmul(w2, w1);
    float2 w4 = cmul(w2, w2);
    float2 w5 = cmul(w4, w1);
    float2 w6 = cmul(w4, w2);
    float2 w7 = cmul(w4, w3);
    float2 w8 = cmul(w4, w4);
    r[1] = cmul(r[1], w1);   r[2] = cmul(r[2], w2);
    r[3] = cmul(r[3], w3);   r[4] = cmul(r[4], w4);
    r[5] = cmul(r[5], w5);   r[6] = cmul(r[6], w6);
    r[7] = cmul(r[7], w7);   r[8] = cmul(r[8], w8);
    r[9]  = cmul(r[9],  cmul(w8, w1));
    r[10] = cmul(r[10], cmul(w8, w2));
    r[11] = cmul(r[11], cmul(w8, w3));
    r[12] = cmul(r[12], cmul(w8, w4));
    r[13] = cmul(r[13], cmul(w8, w5));
    r[14] = cmul(r[14], cmul(w8, w6));
    r[15] = cmul(r[15], cmul(w8, w7));
}

// Fused: one block per PAIR of batches. Coefs computed in-kernel (threads 0 &
// 128, analytic So-inverse), FFT pair trick, fp32 root-shifted H eval:
//   num(z) = sn + (z-1)(n0(z+1) + n1),  den(z) = sd + (z-1)((z+1) + d1)
// with sn,sd accumulated in fp64 (they carry the near-pole cancellation).
__global__ __launch_bounds__(256)
void preamp_fft_kernel(const float* __restrict__ x,
                       const float* __restrict__ state,
                       const float* __restrict__ cond,
                       const float* __restrict__ a_rg,
                       const float* __restrict__ a_r1,
                       const float* __restrict__ a_c1,
                       const float* __restrict__ a_c2,
                       const float* __restrict__ cond_w,
                       const float* __restrict__ cond_b,
                       float* __restrict__ out, int B) {
    __shared__ float2 a_s[NFFT + NFFT / 16];   // padded: 34 KB
    __shared__ float cf[10];                   // 2 batches x {n0,n1,sn,d1,sd}

    const int t = threadIdx.x;
    const int b0 = 2 * blockIdx.x;
    const int b1 = (b0 + 1 < B) ? b0 + 1 : b0;

    const float* st0 = state + (size_t)b0 * SSZ + (SSZ - LSEG);
    const float* xb0 = x + (size_t)b0 * LSEG;
    const float* st1 = state + (size_t)b1 * SSZ + (SSZ - LSEG);
    const float* xb1 = x + (size_t)b1 * LSEG;

    for (int i = t; i < NFFT; i += 256) {
        float fa, fb;
        if (i < LSEG) { fa = st0[i]; fb = st1[i]; }
        else          { fa = xb0[i - LSEG]; fb = xb1[i - LSEG]; }
        a_s[PAD(i)] = make_float2(fa, fb);
    }

    // ---- in-kernel coefficient computation (threads 0 and 128) ----
    if ((t & 127) == 0) {
        const int who = t >> 7;
        const int bb = who ? b1 : b0;

        const double T = 1.0 / 44100.0;
        const double RG = (0.9 + (double)(1.0f / (1.0f + expf(-a_rg[0]))) * 0.2) * 1.0e6;
        const double R1 = (0.99 + (double)(1.0f / (1.0f + expf(-a_r1[0]))) * 0.02) * 4.7e5;
        const double C1 = (0.9 + (double)(1.0f / (1.0f + expf(-a_c1[0]))) * 0.2) * 3.3e-9;
        const double C2 = (0.9 + (double)(1.0f / (1.0f + expf(-a_c2[0]))) * 0.2) * 1.0e-9;
        const double g1 = 1.0 / R1;
        const double gc1 = 2.0 * C1 * 44100.0;  (void)T;
        const double gc2 = 2.0 * C2 * 44100.0;

        float zf = cond[bb] * cond_w[0] + cond_b[0];
        float pot = 1.0f / (1.0f + expf(-zf));
        float prf = (powf(10.0f, pot) - 1.0f) / 9.0f;
        prf = fminf(fmaxf(prf, 1e-4f), 1.0f - 1e-4f);
        const double p = (double)prf;

        // Analytic So^{-1} (column solve of the 4x4 bordered system):
        const double ds = gc1 + g1;
        double S[4][4] = {
            {0.0, 0.0,        0.0,       1.0},
            {0.0, 1.0 / ds,   0.0,       gc1 / ds},
            {0.0, 0.0,        1.0 / gc2, 0.0},
            {1.0, gc1 / ds,   0.0,       -gc1 * g1 / ds}};

        double Q00 = S[1][1] - S[1][2] - S[2][1] + S[2][2];
        double Q01 = S[1][2] - S[2][2];
        double Q10 = S[2][1] - S[2][2];
        double Q11 = S[2][2];

        double Ux00 = S[0][1] - S[0][2] - S[1][1] + S[1][2];
        double Ux01 = S[0][2] - S[1][2];
        double Ux10 = S[2][1] - S[2][2];
        double Ux11 = S[2][2];

        double Uo0 = S[2][1] - S[2][2], Uo1 = S[2][2];
        double Uu0 = S[3][1] - S[3][2], Uu1 = S[3][2];

        double P00 = S[0][0] - S[0][1] - S[1][0] + S[1][1];
        double P01 = S[0][2] - S[1][2];
        double P10 = S[2][0] - S[2][1];
        double P11 = S[2][2];

        double Ao00 = 2.0 * gc1 * P00 - 1.0, Ao01 = 2.0 * gc1 * P01;
        double Ao10 = 2.0 * gc2 * P10,       Ao11 = 2.0 * gc2 * P11 - 1.0;

        double Bo0 = 2.0 * gc1 * (S[0][3] - S[1][3]);
        double Bo1 = 2.0 * gc2 * S[2][3];

        double Do0 = S[2][0] - S[2][1], Do1 = S[2][2];
        double Eo  = S[2][3];

        double T00 = 2.0 * gc1 * Ux00, T01 = 2.0 * gc1 * Ux01;
        double T10 = 2.0 * gc2 * Ux10, T11 = 2.0 * gc2 * Ux11;

        double d0 = (1.0 - p) * RG, d1v = p * RG;
        double M00 = d0 + Q00, M01 = Q01, M10 = Q10, M11 = d1v + Q11;
        double idet = 1.0 / (M00 * M11 - M01 * M10);
        double G00 =  M11 * idet, G01 = -M01 * idet;
        double G10 = -M10 * idet, G11 =  M00 * idet;

        double TG00 = T00 * G00 + T01 * G10, TG01 = T00 * G01 + T01 * G11;
        double TG10 = T10 * G00 + T11 * G10, TG11 = T10 * G01 + T11 * G11;

        double A00 = Ao00 - (TG00 * Ux00 + TG01 * Ux01);
        double A01 = Ao01 - (TG00 * Ux10 + TG01 * Ux11);
        double A10 = Ao10 - (TG10 * Ux00 + TG11 * Ux01);
        double A11 = Ao11 - (TG10 * Ux10 + TG11 * Ux11);

        double Bm0 = Bo0 - (TG00 * Uu0 + TG01 * Uu1);
        double Bm1 = Bo1 - (TG10 * Uu0 + TG11 * Uu1);

        double w0v = Uo0 * G00 + Uo1 * G10, w1v = Uo0 * G01 + Uo1 * G11;
        double Dm0 = Do0 - (w0v * Ux00 + w1v * Ux01);
        double Dm1 = Do1 - (w0v * Ux10 + w1v * Ux11);
        double Em  = Eo  - (w0v * Uu0 + w1v * Uu1);

        double den1 = -(A00 + A11);
        double den2 = A00 * A11 - A01 * A10;
        double Mm00 = A00 - Bm0 * Dm0, Mm01 = A01 - Bm0 * Dm1;
        double Mm10 = A10 - Bm1 * Dm0, Mm11 = A11 - Bm1 * Dm1;
        double num0 = Em;
        double num1 = -(Mm00 + Mm11) + (Em - 1.0) * den1;
        double num2 = (Mm00 * Mm11 - Mm01 * Mm10) + (Em - 1.0) * den2;

        cf[who * 5 + 0] = (float)num0;
        cf[who * 5 + 1] = (float)num1;
        cf[who * 5 + 2] = (float)(num0 + num1 + num2);   // sn = num(1), fp64 sum
        cf[who * 5 + 3] = (float)den1;
        cf[who * 5 + 4] = (float)(1.0 + den1 + den2);    // sd = den(1), fp64 sum
    }
    __syncthreads();

    const float TW4096 = 0.00153398078788564f;   // 2*pi/4096
    const float TW256  = 0.02454369260617026f;   // 2*pi/256
    const float HW4096 = 0.00076699039394282f;   // pi/4096

    float2 r[16];

    // ---- forward pass A: span 256 ----
#pragma unroll
    for (int m = 0; m < 16; ++m) r[m] = a_s[PAD(t + 256 * m)];
    dft16<-1>(r);
    {
        float sw, cw;
        __sincosf((float)t * TW4096, &sw, &cw);
        twiddle_chain(r, make_float2(cw, -sw));
    }
#pragma unroll
    for (int m = 0; m < 16; ++m) a_s[PAD(t + 256 * m)] = r[m];
    __syncthreads();

    // ---- forward pass B: span 16 within 256-blocks ----
    {
        const int sub = t >> 4, j = t & 15;
        const int base = sub * 256 + j;
#pragma unroll
        for (int m = 0; m < 16; ++m) r[m] = a_s[PAD(base + 16 * m)];
        dft16<-1>(r);
        float sw, cw;
        __sincosf((float)j * TW256, &sw, &cw);
        twiddle_chain(r, make_float2(cw, -sw));
#pragma unroll
        for (int m = 0; m < 16; ++m) a_s[PAD(base + 16 * m)] = r[m];
    }
    __syncthreads();

    // ---- forward span-1 DFT, scatter to natural order ----
    {
        const int base = 16 * t;
#pragma unroll
        for (int m = 0; m < 16; ++m) r[m] = a_s[PAD(base + m)];
        dft16<-1>(r);
        const int klo = ((t & 15) << 4) | (t >> 4);
        __syncthreads();
#pragma unroll
        for (int m = 0; m < 16; ++m) a_s[PAD((m << 8) | klo)] = r[m];
    }
    __syncthreads();

    // ---- pointwise in natural order over Hermitian pairs (k, N-k), fp32 ----
    {
        const float an0 = cf[0], an1 = cf[1], asn = cf[2], ad1 = cf[3], asd = cf[4];
        const float bn0 = cf[5], bn1 = cf[6], bsn = cf[7], bd1 = cf[8], bsd = cf[9];

        for (int i = t; i <= HALF; i += 256) {
            const int k  = i;
            const int kr = (NFFT - i) & (NFFT - 1);
            float2 Wk = a_s[PAD(k)];
            float2 Wr = a_s[PAD(kr)];
            // Hermitian split
            float Xar = 0.5f * (Wk.x + Wr.x), Xai = 0.5f * (Wk.y - Wr.y);
            float Xbr = 0.5f * (Wk.y + Wr.y), Xbi = 0.5f * (Wr.x - Wk.x);
            // u = z-1 = -2*sin(th/2)*(sin(th/2), cos(th/2)), z = e^{-i th}
            float sh, ch;
            __sincosf((float)k * HW4096, &sh, &ch);
            float m2s = -2.0f * sh;
            float ur = m2s * sh, ui = m2s * ch;
            float pr = ur + 2.0f;           // Re(z+1); Im(z+1) = ui
            // batch a: H = (sn + u*(n0*(z+1)+n1)) / (sd + u*((z+1)+d1))
            float tar = an0 * pr + an1, tai = an0 * ui;
            float nr = asn + ur * tar - ui * tai, ni = ur * tai + ui * tar;
            float tbr = pr + ad1;
            float dr = asd + ur * tbr - ui * ui, di = ur * ui + ui * tbr;
            float inv = __builtin_amdgcn_rcpf(dr * dr + di * di);
            float Har = (nr * dr + ni * di) * inv, Hai = (ni * dr - nr * di) * inv;
            // batch b
            tar = bn0 * pr + bn1; tai = bn0 * ui;
            nr = bsn + ur * tar - ui * tai; ni = ur * tai + ui * tar;
            tbr = pr + bd1;
            dr = bsd + ur * tbr - ui * ui; di = ur * ui + ui * tbr;
            inv = __builtin_amdgcn_rcpf(dr * dr + di * di);
            float Hbr = (nr * dr + ni * di) * inv, Hbi = (ni * dr - nr * di) * inv;

            float Yar = Har * Xar - Hai * Xai, Yai = Har * Xai + Hai * Xar;
            float Ybr = Hbr * Xbr - Hbi * Xbi, Ybi = Hbr * Xbi + Hbi * Xbr;
            // Y[k] = Ya + i*Yb ; Y[N-k] = conj(Ya) + i*conj(Yb)
            a_s[PAD(k)] = make_float2(Yar - Ybi, Yai + Ybr);
            if (kr != k) a_s[PAD(kr)] = make_float2(Yar + Ybi, Ybr - Yai);
        }
    }
    __syncthreads();

    // ---- inverse span-1: gather from natural order, DFT, store base layout ----
    {
        const int base = 16 * t;
        const int klo = ((t & 15) << 4) | (t >> 4);
#pragma unroll
        for (int m = 0; m < 16; ++m) r[m] = a_s[PAD((m << 8) | klo)];
        dft16<1>(r);
        __syncthreads();
#pragma unroll
        for (int m = 0; m < 16; ++m) a_s[PAD(base + m)] = r[m];
    }
    __syncthreads();

    // ---- inverse pass B ----
    {
        const int sub = t >> 4, j = t & 15;
        const int base = sub * 256 + j;
#pragma unroll
        for (int m = 0; m < 16; ++m) r[m] = a_s[PAD(base + 16 * m)];
        float sw, cw;
        __sincosf((float)j * TW256, &sw, &cw);
        twiddle_chain(r, make_float2(cw, sw));
        dft16<1>(r);
#pragma unroll
        for (int m = 0; m < 16; ++m) a_s[PAD(base + 16 * m)] = r[m];
    }
    __syncthreads();

    // ---- inverse pass A + direct store of last 2048 samples of both batches ----
    {
#pragma unroll
        for (int m = 0; m < 16; ++m) r[m] = a_s[PAD(t + 256 * m)];
        float sw, cw;
        __sincosf((float)t * TW4096, &sw, &cw);
        twiddle_chain(r, make_float2(cw, sw));
        dft16<1>(r);
        const float scale = 1.0f / (float)NFFT;
        float* ob0 = out + (size_t)b0 * LSEG;
        float* ob1 = out + (size_t)b1 * LSEG;
#pragma unroll
        for (int m = 8; m < 16; ++m) {
            ob0[t + 256 * (m - 8)] = r[m].x * scale;
            if (b1 != b0) ob1[t + 256 * (m - 8)] = r[m].y * scale;
        }
    }
}

extern "C" void kernel_launch(void* const* d_in, const int* in_sizes, int n_in,
                              void* d_out, int out_size, void* d_ws, size_t ws_size,
                              hipStream_t stream) {
    const float* x     = (const float*)d_in[0];
    const float* cond  = (const float*)d_in[1];
    const float* state = (const float*)d_in[2];
    const float* a_rg  = (const float*)d_in[3];
    const float* a_r1  = (const float*)d_in[4];
    const float* a_c1  = (const float*)d_in[5];
    const float* a_c2  = (const float*)d_in[6];
    const float* c_w   = (const float*)d_in[7];
    const float* c_b   = (const float*)d_in[8];
    float* out = (float*)d_out;

    const int B = in_sizes[1];          // cond is [B,1]

    preamp_fft_kernel<<<dim3((B + 1) / 2), dim3(256), 0, stream>>>(
        x, state, cond, a_rg, a_r1, a_c1, a_c2, c_w, c_b, out, B);
}

// Round 6
// 118.674 us; speedup vs baseline: 2.1196x; 1.0233x over previous
//
#include <hip/hip_runtime.h>
#include <math.h>

#define NFFT 4096
#define HALF 2048
#define LSEG 2048   // L
#define SSZ 4096    // STATE_SIZE

typedef float v2f __attribute__((ext_vector_type(2)));

// ---------------- radix-16 FFT machinery (packed-f32 complex) ----------------

static __device__ __forceinline__ v2f cmul(v2f a, v2f b) {
    return (v2f){ fmaf(-a.y, b.y, a.x * b.x), fmaf(a.y, b.x, a.x * b.y) };
}

static __device__ __forceinline__ int PAD(int i) { return i + (i >> 4); }

template <int SGN>
static __device__ __forceinline__ void dft16(v2f r[16]) {
    const float S = (float)SGN;
    v2f t[16];
#pragma unroll
    for (int n1 = 0; n1 < 4; ++n1) {
        v2f a = r[n1], b = r[n1 + 4], c = r[n1 + 8], d = r[n1 + 12];
        v2f A = a + c, B = b + d, C = a - c, D = b - d;
        v2f iD = (v2f){ -S * D.y, S * D.x };
        t[n1 * 4 + 0] = A + B;
        t[n1 * 4 + 1] = C + iD;
        t[n1 * 4 + 2] = A - B;
        t[n1 * 4 + 3] = C - iD;
    }
    const float CC[10] = {1.f, 0.92387953251f, 0.70710678119f, 0.38268343236f, 0.f,
                          -0.38268343236f, -0.70710678119f, -0.92387953251f, -1.f, -0.92387953251f};
    const float SS[10] = {0.f, 0.38268343236f, 0.70710678119f, 0.92387953251f, 1.f,
                          0.92387953251f, 0.70710678119f, 0.38268343236f, 0.f, -0.38268343236f};
#pragma unroll
    for (int n1 = 1; n1 < 4; ++n1) {
#pragma unroll
        for (int m2 = 1; m2 < 4; ++m2) {
            const int k = n1 * m2;
            t[n1 * 4 + m2] = cmul(t[n1 * 4 + m2], (v2f){CC[k], S * SS[k]});
        }
    }
#pragma unroll
    for (int m2 = 0; m2 < 4; ++m2) {
        v2f a = t[m2], b = t[4 + m2], c = t[8 + m2], d = t[12 + m2];
        v2f A = a + c, B = b + d, C = a - c, D = b - d;
        v2f iD = (v2f){ -S * D.y, S * D.x };
        r[m2]      = A + B;
        r[m2 + 4]  = C + iD;
        r[m2 + 8]  = A - B;
        r[m2 + 12] = C - iD;
    }
}

// apply r[m] *= w1^m via squaring tree (depth 4)
static __device__ __forceinline__ void twiddle_chain(v2f r[16], v2f w1) {
    v2f w2 = cmul(w1, w1);
    v2f w3 = cmul(w2, w1);
    v2f w4 = cmul(w2, w2);
    v2f w5 = cmul(w4, w1);
    v2f w6 = cmul(w4, w2);
    v2f w7 = cmul(w4, w3);
    v2f w8 = cmul(w4, w4);
    r[1] = cmul(r[1], w1);   r[2] = cmul(r[2], w2);
    r[3] = cmul(r[3], w3);   r[4] = cmul(r[4], w4);
    r[5] = cmul(r[5], w5);   r[6] = cmul(r[6], w6);
    r[7] = cmul(r[7], w7);   r[8] = cmul(r[8], w8);
    r[9]  = cmul(r[9],  cmul(w8, w1));
    r[10] = cmul(r[10], cmul(w8, w2));
    r[11] = cmul(r[11], cmul(w8, w3));
    r[12] = cmul(r[12], cmul(w8, w4));
    r[13] = cmul(r[13], cmul(w8, w5));
    r[14] = cmul(r[14], cmul(w8, w6));
    r[15] = cmul(r[15], cmul(w8, w7));
}

// Fused: one block per PAIR of batches. Coefs computed in-kernel (threads 0 &
// 128, analytic So-inverse), FFT pair trick, fp32 root-shifted H eval:
//   num(z) = sn + (z-1)(n0(z+1) + n1),  den(z) = sd + (z-1)((z+1) + d1)
// with sn,sd accumulated in fp64 (they carry the near-pole cancellation).
__global__ __launch_bounds__(256)
void preamp_fft_kernel(const float* __restrict__ x,
                       const float* __restrict__ state,
                       const float* __restrict__ cond,
                       const float* __restrict__ a_rg,
                       const float* __restrict__ a_r1,
                       const float* __restrict__ a_c1,
                       const float* __restrict__ a_c2,
                       const float* __restrict__ cond_w,
                       const float* __restrict__ cond_b,
                       float* __restrict__ out, int B) {
    __shared__ v2f a_s[NFFT + NFFT / 16];   // padded: 34 KB
    __shared__ float cf[10];                // 2 batches x {n0,n1,sn,d1,sd}

    const int t = threadIdx.x;
    const int b0 = 2 * blockIdx.x;
    const int b1 = (b0 + 1 < B) ? b0 + 1 : b0;

    const float* st0 = state + (size_t)b0 * SSZ + (SSZ - LSEG);
    const float* xb0 = x + (size_t)b0 * LSEG;
    const float* st1 = state + (size_t)b1 * SSZ + (SSZ - LSEG);
    const float* xb1 = x + (size_t)b1 * LSEG;

    for (int i = t; i < NFFT; i += 256) {
        float fa, fb;
        if (i < LSEG) { fa = st0[i]; fb = st1[i]; }
        else          { fa = xb0[i - LSEG]; fb = xb1[i - LSEG]; }
        a_s[PAD(i)] = (v2f){fa, fb};
    }

    // ---- in-kernel coefficient computation (threads 0 and 128) ----
    if ((t & 127) == 0) {
        const int who = t >> 7;
        const int bb = who ? b1 : b0;

        const double RG = (0.9 + (double)(1.0f / (1.0f + expf(-a_rg[0]))) * 0.2) * 1.0e6;
        const double R1 = (0.99 + (double)(1.0f / (1.0f + expf(-a_r1[0]))) * 0.02) * 4.7e5;
        const double C1 = (0.9 + (double)(1.0f / (1.0f + expf(-a_c1[0]))) * 0.2) * 3.3e-9;
        const double C2 = (0.9 + (double)(1.0f / (1.0f + expf(-a_c2[0]))) * 0.2) * 1.0e-9;
        const double g1 = 1.0 / R1;
        const double gc1 = 2.0 * C1 * 44100.0;
        const double gc2 = 2.0 * C2 * 44100.0;

        float zf = cond[bb] * cond_w[0] + cond_b[0];
        float pot = 1.0f / (1.0f + expf(-zf));
        float prf = (powf(10.0f, pot) - 1.0f) / 9.0f;
        prf = fminf(fmaxf(prf, 1e-4f), 1.0f - 1e-4f);
        const double p = (double)prf;

        // Analytic So^{-1}
        const double ds = gc1 + g1;
        double S[4][4] = {
            {0.0, 0.0,        0.0,       1.0},
            {0.0, 1.0 / ds,   0.0,       gc1 / ds},
            {0.0, 0.0,        1.0 / gc2, 0.0},
            {1.0, gc1 / ds,   0.0,       -gc1 * g1 / ds}};

        double Q00 = S[1][1] - S[1][2] - S[2][1] + S[2][2];
        double Q01 = S[1][2] - S[2][2];
        double Q10 = S[2][1] - S[2][2];
        double Q11 = S[2][2];

        double Ux00 = S[0][1] - S[0][2] - S[1][1] + S[1][2];
        double Ux01 = S[0][2] - S[1][2];
        double Ux10 = S[2][1] - S[2][2];
        double Ux11 = S[2][2];

        double Uo0 = S[2][1] - S[2][2], Uo1 = S[2][2];
        double Uu0 = S[3][1] - S[3][2], Uu1 = S[3][2];

        double P00 = S[0][0] - S[0][1] - S[1][0] + S[1][1];
        double P01 = S[0][2] - S[1][2];
        double P10 = S[2][0] - S[2][1];
        double P11 = S[2][2];

        double Ao00 = 2.0 * gc1 * P00 - 1.0, Ao01 = 2.0 * gc1 * P01;
        double Ao10 = 2.0 * gc2 * P10,       Ao11 = 2.0 * gc2 * P11 - 1.0;

        double Bo0 = 2.0 * gc1 * (S[0][3] - S[1][3]);
        double Bo1 = 2.0 * gc2 * S[2][3];

        double Do0 = S[2][0] - S[2][1], Do1 = S[2][2];
        double Eo  = S[2][3];

        double T00 = 2.0 * gc1 * Ux00, T01 = 2.0 * gc1 * Ux01;
        double T10 = 2.0 * gc2 * Ux10, T11 = 2.0 * gc2 * Ux11;

        double d0 = (1.0 - p) * RG, d1v = p * RG;
        double M00 = d0 + Q00, M01 = Q01, M10 = Q10, M11 = d1v + Q11;
        double idet = 1.0 / (M00 * M11 - M01 * M10);
        double G00 =  M11 * idet, G01 = -M01 * idet;
        double G10 = -M10 * idet, G11 =  M00 * idet;

        double TG00 = T00 * G00 + T01 * G10, TG01 = T00 * G01 + T01 * G11;
        double TG10 = T10 * G00 + T11 * G10, TG11 = T10 * G01 + T11 * G11;

        double A00 = Ao00 - (TG00 * Ux00 + TG01 * Ux01);
        double A01 = Ao01 - (TG00 * Ux10 + TG01 * Ux11);
        double A10 = Ao10 - (TG10 * Ux00 + TG11 * Ux01);
        double A11 = Ao11 - (TG10 * Ux10 + TG11 * Ux11);

        double Bm0 = Bo0 - (TG00 * Uu0 + TG01 * Uu1);
        double Bm1 = Bo1 - (TG10 * Uu0 + TG11 * Uu1);

        double w0v = Uo0 * G00 + Uo1 * G10, w1v = Uo0 * G01 + Uo1 * G11;
        double Dm0 = Do0 - (w0v * Ux00 + w1v * Ux01);
        double Dm1 = Do1 - (w0v * Ux10 + w1v * Ux11);
        double Em  = Eo  - (w0v * Uu0 + w1v * Uu1);

        double den1 = -(A00 + A11);
        double den2 = A00 * A11 - A01 * A10;
        double Mm00 = A00 - Bm0 * Dm0, Mm01 = A01 - Bm0 * Dm1;
        double Mm10 = A10 - Bm1 * Dm0, Mm11 = A11 - Bm1 * Dm1;
        double num0 = Em;
        double num1 = -(Mm00 + Mm11) + (Em - 1.0) * den1;
        double num2 = (Mm00 * Mm11 - Mm01 * Mm10) + (Em - 1.0) * den2;

        cf[who * 5 + 0] = (float)num0;
        cf[who * 5 + 1] = (float)num1;
        cf[who * 5 + 2] = (float)(num0 + num1 + num2);   // sn = num(1), fp64 sum
        cf[who * 5 + 3] = (float)den1;
        cf[who * 5 + 4] = (float)(1.0 + den1 + den2);    // sd = den(1), fp64 sum
    }
    __syncthreads();

    const float TW4096 = 0.00153398078788564f;   // 2*pi/4096
    const float TW256  = 0.02454369260617026f;   // 2*pi/256
    const float HW4096 = 0.00076699039394282f;   // pi/4096

    v2f r[16];

    // ---- forward pass A: span 256 ----
#pragma unroll
    for (int m = 0; m < 16; ++m) r[m] = a_s[PAD(t + 256 * m)];
    dft16<-1>(r);
    {
        float sw, cw;
        __sincosf((float)t * TW4096, &sw, &cw);
        twiddle_chain(r, (v2f){cw, -sw});
    }
#pragma unroll
    for (int m = 0; m < 16; ++m) a_s[PAD(t + 256 * m)] = r[m];
    __syncthreads();

    // ---- forward pass B: span 16 within 256-blocks ----
    {
        const int sub = t >> 4, j = t & 15;
        const int base = sub * 256 + j;
#pragma unroll
        for (int m = 0; m < 16; ++m) r[m] = a_s[PAD(base + 16 * m)];
        dft16<-1>(r);
        float sw, cw;
        __sincosf((float)j * TW256, &sw, &cw);
        twiddle_chain(r, (v2f){cw, -sw});
#pragma unroll
        for (int m = 0; m < 16; ++m) a_s[PAD(base + 16 * m)] = r[m];
    }
    __syncthreads();

    // ---- forward span-1 DFT, scatter to natural order ----
    {
        const int base = 16 * t;
#pragma unroll
        for (int m = 0; m < 16; ++m) r[m] = a_s[PAD(base + m)];
        dft16<-1>(r);
        const int klo = ((t & 15) << 4) | (t >> 4);
        __syncthreads();
#pragma unroll
        for (int m = 0; m < 16; ++m) a_s[PAD((m << 8) | klo)] = r[m];
    }
    __syncthreads();

    // ---- pointwise in natural order over Hermitian pairs (k, N-k), fp32 ----
    {
        const float an0 = cf[0], an1 = cf[1], asn = cf[2], ad1 = cf[3], asd = cf[4];
        const float bn0 = cf[5], bn1 = cf[6], bsn = cf[7], bd1 = cf[8], bsd = cf[9];

        for (int i = t; i <= HALF; i += 256) {
            const int k  = i;
            const int kr = (NFFT - i) & (NFFT - 1);
            v2f Wk = a_s[PAD(k)];
            v2f Wr = a_s[PAD(kr)];
            // Hermitian split
            float Xar = 0.5f * (Wk.x + Wr.x), Xai = 0.5f * (Wk.y - Wr.y);
            float Xbr = 0.5f * (Wk.y + Wr.y), Xbi = 0.5f * (Wr.x - Wk.x);
            // u = z-1 = -2*sin(th/2)*(sin(th/2), cos(th/2)), z = e^{-i th}
            float sh, ch;
            __sincosf((float)k * HW4096, &sh, &ch);
            float m2s = -2.0f * sh;
            float ur = m2s * sh, ui = m2s * ch;
            float pr = ur + 2.0f;           // Re(z+1); Im(z+1) = ui
            // batch a: H = (sn + u*(n0*(z+1)+n1)) / (sd + u*((z+1)+d1))
            float tar = an0 * pr + an1, tai = an0 * ui;
            float nr = asn + ur * tar - ui * tai, ni = ur * tai + ui * tar;
            float tbr = pr + ad1;
            float dr = asd + ur * tbr - ui * ui, di = ur * ui + ui * tbr;
            float inv = __builtin_amdgcn_rcpf(dr * dr + di * di);
            float Har = (nr * dr + ni * di) * inv, Hai = (ni * dr - nr * di) * inv;
            // batch b
            tar = bn0 * pr + bn1; tai = bn0 * ui;
            nr = bsn + ur * tar - ui * tai; ni = ur * tai + ui * tar;
            tbr = pr + bd1;
            dr = bsd + ur * tbr - ui * ui; di = ur * ui + ui * tbr;
            inv = __builtin_amdgcn_rcpf(dr * dr + di * di);
            float Hbr = (nr * dr + ni * di) * inv, Hbi = (ni * dr - nr * di) * inv;

            float Yar = Har * Xar - Hai * Xai, Yai = Har * Xai + Hai * Xar;
            float Ybr = Hbr * Xbr - Hbi * Xbi, Ybi = Hbr * Xbi + Hbi * Xbr;
            // Y[k] = Ya + i*Yb ; Y[N-k] = conj(Ya) + i*conj(Yb)
            a_s[PAD(k)] = (v2f){Yar - Ybi, Yai + Ybr};
            if (kr != k) a_s[PAD(kr)] = (v2f){Yar + Ybi, Ybr - Yai};
        }
    }
    __syncthreads();

    // ---- inverse span-1: gather from natural order, DFT, store base layout ----
    {
        const int base = 16 * t;
        const int klo = ((t & 15) << 4) | (t >> 4);
#pragma unroll
        for (int m = 0; m < 16; ++m) r[m] = a_s[PAD((m << 8) | klo)];
        dft16<1>(r);
        __syncthreads();
#pragma unroll
        for (int m = 0; m < 16; ++m) a_s[PAD(base + m)] = r[m];
    }
    __syncthreads();

    // ---- inverse pass B ----
    {
        const int sub = t >> 4, j = t & 15;
        const int base = sub * 256 + j;
#pragma unroll
        for (int m = 0; m < 16; ++m) r[m] = a_s[PAD(base + 16 * m)];
        float sw, cw;
        __sincosf((float)j * TW256, &sw, &cw);
        twiddle_chain(r, (v2f){cw, sw});
        dft16<1>(r);
#pragma unroll
        for (int m = 0; m < 16; ++m) a_s[PAD(base + 16 * m)] = r[m];
    }
    __syncthreads();

    // ---- inverse pass A + direct store of last 2048 samples of both batches ----
    {
#pragma unroll
        for (int m = 0; m < 16; ++m) r[m] = a_s[PAD(t + 256 * m)];
        float sw, cw;
        __sincosf((float)t * TW4096, &sw, &cw);
        twiddle_chain(r, (v2f){cw, sw});
        dft16<1>(r);
        const float scale = 1.0f / (float)NFFT;
        float* ob0 = out + (size_t)b0 * LSEG;
        // second stream: write to b1's row; if b1==b0 (odd tail) write same value
        float* ob1 = out + (size_t)b1 * LSEG;
#pragma unroll
        for (int m = 8; m < 16; ++m) {
            const int idx = t + 256 * (m - 8);
            float ya = r[m].x * scale;
            float yb = (b1 != b0) ? r[m].y * scale : ya;
            ob0[idx] = ya;
            ob1[idx] = yb;
        }
    }
}

extern "C" void kernel_launch(void* const* d_in, const int* in_sizes, int n_in,
                              void* d_out, int out_size, void* d_ws, size_t ws_size,
                              hipStream_t stream) {
    const float* x     = (const float*)d_in[0];
    const float* cond  = (const float*)d_in[1];
    const float* state = (const float*)d_in[2];
    const float* a_rg  = (const float*)d_in[3];
    const float* a_r1  = (const float*)d_in[4];
    const float* a_c1  = (const float*)d_in[5];
    const float* a_c2  = (const float*)d_in[6];
    const float* c_w   = (const float*)d_in[7];
    const float* c_b   = (const float*)d_in[8];
    float* out = (float*)d_out;

    const int B = in_sizes[1];          // cond is [B,1]

    preamp_fft_kernel<<<dim3((B + 1) / 2), dim3(256), 0, stream>>>(
        x, state, cond, a_rg, a_r1, a_c1, a_c2, c_w, c_b, out, B);
}